// Round 7
// baseline (142.253 us; speedup 1.0000x reference)
//
#include <hip/hip_runtime.h>
#include <math.h>

// Problem dims (fixed by the reference)
#define SEQ   512
#define BATCH 1024
#define NFEAT 128
#define HID   20
#define NCLS  10

typedef __attribute__((ext_vector_type(8))) short short8v;  // 8 bf16 (4 VGPR)
typedef __attribute__((ext_vector_type(4))) float f32x4;    // MFMA 16x16 acc
typedef __attribute__((ext_vector_type(4))) unsigned int u32x4;

#define AS1 __attribute__((address_space(1)))
#define AS3 __attribute__((address_space(3)))

__device__ __forceinline__ float truncbf(float f) {
  return __uint_as_float(__float_as_uint(f) & 0xffff0000u);
}
__device__ __forceinline__ unsigned packhi2(float a, float b) {
  return (__float_as_uint(a) >> 16) | (__float_as_uint(b) & 0xffff0000u);
}
__device__ __forceinline__ short8v mk8(unsigned a, unsigned b, unsigned c, unsigned d) {
  u32x4 u; u[0] = a; u[1] = b; u[2] = c; u[3] = d;
  return __builtin_bit_cast(short8v, u);
}
// fp32 octet -> (hi bf16x8, lo bf16x8); x == hi + lo to ~2^-17 rel
__device__ __forceinline__ void cvt_hilo(float4 ca, float4 cb, short8v& hi, short8v& lo) {
  hi = mk8(packhi2(ca.x, ca.y), packhi2(ca.z, ca.w),
           packhi2(cb.x, cb.y), packhi2(cb.z, cb.w));
  const float l0 = ca.x - truncbf(ca.x);
  const float l1 = ca.y - truncbf(ca.y);
  const float l2 = ca.z - truncbf(ca.z);
  const float l3 = ca.w - truncbf(ca.w);
  const float l4 = cb.x - truncbf(cb.x);
  const float l5 = cb.y - truncbf(cb.y);
  const float l6 = cb.z - truncbf(cb.z);
  const float l7 = cb.w - truncbf(cb.w);
  lo = mk8(packhi2(l0, l1), packhi2(l2, l3), packhi2(l4, l5), packhi2(l6, l7));
}

// ---------------------------------------------------------------------------
// Kernel A (MFMA + global_load_lds deep pipeline):
//   xp = 2*(x @ W_ih^T + b_ih + b_hh)
// R6 post-mortem: all register-staged variants cap at ~3.5 TB/s because the
// schedule covers only ~600 cyc of a 2000-3000 cyc LOADED HBM latency.
// This version: per-wave-private 4x8KB LDS ring, global_load_lds (width 16,
// no VGPR round-trip, no barriers ever), 3 tiles always in flight, and
// HAND-COUNTED vmcnt waits exploiting in-order vmcnt retirement:
//   program order (fenced):  [w] S(t) | L(t+3) | [w] S(t+1) | L(t+4) ...
//   newer-than-L(t) at its wait = S(t-2)+L(t+1)+S(t-1)+L(t+2) = 32
// so s_waitcnt vmcnt(32) == "tile t resident in LDS", never a drain.
// Global source is pre-swizzled per-lane / LDS dest linear (rule 21); the
// swizzled ds_read_b128 fragment reads are ~2-way (free). Swizzle algebra
// identical to R6 (correctness-verified).
// ---------------------------------------------------------------------------
#define TPW  16   // 16-row tiles per wave
#define NBUF 4    // LDS ring depth (8KB each)

__global__ __launch_bounds__(64) void k_input_proj(
    const float* __restrict__ x, const float* __restrict__ W_ih,
    const float* __restrict__ b_ih, const float* __restrict__ b_hh,
    float* __restrict__ xp)
{
  __shared__ __align__(16) char lds[NBUF * 8192];   // 32KB, 1 wave per block
  const int lane = threadIdx.x;   // 0..63
  const int rr   = lane & 15;     // A-row within tile / C-col
  const int kq   = lane >> 4;     // k-group (0..3), 8 k's each

  // ---- W -> resident B fragments (hi/lo, 2 n-tiles x 4 k-chunks)
  short8v Bhi[2][4], Blo[2][4];
#pragma unroll
  for (int nt = 0; nt < 2; ++nt) {
    const int n = nt * 16 + rr;
    const bool v = (n < HID);
#pragma unroll
    for (int k = 0; k < 4; ++k) {
      float4 wa = {0.f, 0.f, 0.f, 0.f}, wb = {0.f, 0.f, 0.f, 0.f};
      if (v) {
        const float* wp = W_ih + n * NFEAT + k * 32 + kq * 8;
        wa = *reinterpret_cast<const float4*>(wp);
        wb = *reinterpret_cast<const float4*>(wp + 4);
      }
      cvt_hilo(wa, wb, Bhi[nt][k], Blo[nt][k]);
    }
  }

  const float badd0 = b_ih[rr] + b_hh[rr];
  const int   n1    = 16 + rr;
  const float badd1 = (n1 < HID) ? (b_ih[n1] + b_hh[n1]) : 0.0f;

  const int t0 = blockIdx.x * TPW;

  // pre-swizzled per-lane global source offsets: f(A)=A^(((A>>9)&7)<<4)
  int srcoff[8];
#pragma unroll
  for (int jj = 0; jj < 8; ++jj)
    srcoff[jj] = (jj * 1024 + lane * 16) ^ (((2 * jj + (lane >> 5)) & 7) << 4);

  // swizzled read bases (logical L = rr*512 + kq*32 (+16); phys = f(L))
  const int rdp0 = (rr * 512 + kq * 32)      ^ ((rr & 7) << 4);
  const int rdp1 = (rr * 512 + kq * 32 + 16) ^ ((rr & 7) << 4);

  const char* __restrict__ xb = reinterpret_cast<const char*>(x);

#define VM_WAIT(N)  asm volatile("s_waitcnt vmcnt(" #N ")" ::: "memory")
#define MEMFENCE()  asm volatile("" ::: "memory")

// 8KB tile T -> LDS ring slot (T&3) via direct HBM->LDS DMA (8 x 1KB instr)
#define LOADL(T) {                                                             \
    const char* gp_ = xb + (size_t)(t0 + (T)) * 8192;                          \
    char* lb_ = lds + ((T) & (NBUF - 1)) * 8192;                               \
    _Pragma("unroll")                                                          \
    for (int jj = 0; jj < 8; ++jj)                                             \
      __builtin_amdgcn_global_load_lds(                                        \
          (const AS1 void*)(gp_ + srcoff[jj]),                                 \
          (AS3 void*)(lb_ + jj * 1024), 16, 0, 0); }

#define COMPSTORE(T) {                                                         \
    const char* lb_ = lds + ((T) & (NBUF - 1)) * 8192;                         \
    f32x4 acc0 = {0.f, 0.f, 0.f, 0.f};                                         \
    f32x4 acc1 = {0.f, 0.f, 0.f, 0.f};                                         \
    _Pragma("unroll")                                                          \
    for (int k = 0; k < 4; ++k) {                                              \
      const float4 ca = *reinterpret_cast<const float4*>(lb_ + rdp0 + k * 128);\
      const float4 cb = *reinterpret_cast<const float4*>(lb_ + rdp1 + k * 128);\
      short8v Ahi, Alo;                                                        \
      cvt_hilo(ca, cb, Ahi, Alo);                                              \
      acc0 = __builtin_amdgcn_mfma_f32_16x16x32_bf16(Ahi, Bhi[0][k], acc0, 0, 0, 0); \
      acc0 = __builtin_amdgcn_mfma_f32_16x16x32_bf16(Ahi, Blo[0][k], acc0, 0, 0, 0); \
      acc0 = __builtin_amdgcn_mfma_f32_16x16x32_bf16(Alo, Bhi[0][k], acc0, 0, 0, 0); \
      acc1 = __builtin_amdgcn_mfma_f32_16x16x32_bf16(Ahi, Bhi[1][k], acc1, 0, 0, 0); \
      acc1 = __builtin_amdgcn_mfma_f32_16x16x32_bf16(Ahi, Blo[1][k], acc1, 0, 0, 0); \
      acc1 = __builtin_amdgcn_mfma_f32_16x16x32_bf16(Alo, Bhi[1][k], acc1, 0, 0, 0); \
    }                                                                          \
    const int R = (t0 + (T)) * 16;                                             \
    _Pragma("unroll")                                                          \
    for (int reg = 0; reg < 4; ++reg) {                                        \
      float* prow = xp + (size_t)(R + kq * 4 + reg) * HID;                     \
      prow[rr] = 2.0f * (acc0[reg] + badd0);                                   \
      if (n1 < HID) prow[n1] = 2.0f * (acc1[reg] + badd1);                     \
    } }

  // ---- pipeline: 3 tiles in flight, counted waits, zero drains ----
  LOADL(0); LOADL(1); LOADL(2);
  VM_WAIT(16); COMPSTORE(0); MEMFENCE(); LOADL(3);
  VM_WAIT(24); COMPSTORE(1); MEMFENCE(); LOADL(4);
  for (int t = 2; t <= TPW - 4; ++t) {
    VM_WAIT(32); COMPSTORE(t); MEMFENCE(); LOADL(t + 3);
  }
  VM_WAIT(32); COMPSTORE(TPW - 3);
  VM_WAIT(24); COMPSTORE(TPW - 2);
  VM_WAIT(16); COMPSTORE(TPW - 1);

#undef LOADL
#undef COMPSTORE
#undef VM_WAIT
#undef MEMFENCE
}

// ---------------------------------------------------------------------------
// Kernel B: 512-step recurrence + final FC (unchanged from R6, passed).
// 1 wave/block, 3 batches/wave, lane j owns h[j] + 2*W_hh row j in VGPRs;
// h exchanged via 1 ds_write + 5 conflict-free broadcast ds_read_b128/step.
// xp arrives pre-scaled by 2, so tanh(s) = (e^{s'}-1)/(e^{s'}+1), s'=2s.
// ---------------------------------------------------------------------------
#define BPW 3   // batches per wave
#define PF  8   // xp prefetch chunk (steps)

__device__ __forceinline__ float tanh_scaled(float sp) {  // sp = 2*s
  sp = fminf(fmaxf(sp, -18.0f), 18.0f);
  const float e = __expf(sp);
  return (e - 1.0f) * __builtin_amdgcn_rcpf(e + 1.0f);
}

__global__ __launch_bounds__(64) void k_rnn_scan(
    const float* __restrict__ xp, const float* __restrict__ W_hh,
    const float* __restrict__ W_fc, const float* __restrict__ b_fc,
    float* __restrict__ out)
{
  __shared__ __align__(16) float hsh[4][HID];  // [group][h]
  const int lane = threadIdx.x;
  const int g = lane / HID;        // 0..3
  const int j = lane - g * HID;    // 0..19
  const int b = blockIdx.x * BPW + g;
  const bool valid = (g < BPW) && (b < BATCH);
  const int beff = valid ? b : 0;

  // W_hh row j -> registers, pre-scaled by 2
  float w[HID];
  {
    const float4* wr = reinterpret_cast<const float4*>(W_hh + j * HID);
#pragma unroll
    for (int qq = 0; qq < HID / 4; ++qq) {
      const float4 v = wr[qq];
      w[qq * 4 + 0] = 2.0f * v.x; w[qq * 4 + 1] = 2.0f * v.y;
      w[qq * 4 + 2] = 2.0f * v.z; w[qq * 4 + 3] = 2.0f * v.w;
    }
  }

  hsh[g][j] = 0.0f;
  __builtin_amdgcn_wave_barrier();

  const float* __restrict__ xl = xp + beff * HID + j;
  const int STRIDE = BATCH * HID;
  const float4* __restrict__ hp = reinterpret_cast<const float4*>(&hsh[g][0]);

  float bufA[PF], bufB[PF];

#define STEPF(XV)                                                              \
  {                                                                            \
    float4 h0 = hp[0], h1 = hp[1], h2 = hp[2], h3 = hp[3], h4 = hp[4];         \
    float a0 = fmaf(w[3], h0.w, fmaf(w[2], h0.z, fmaf(w[1], h0.y, fmaf(w[0], h0.x, (XV))))); \
    float a1 = fmaf(w[7], h1.w, fmaf(w[6], h1.z, fmaf(w[5], h1.y, w[4] * h1.x)));            \
    float a2 = fmaf(w[11], h2.w, fmaf(w[10], h2.z, fmaf(w[9], h2.y, w[8] * h2.x)));          \
    float a3 = fmaf(w[15], h3.w, fmaf(w[14], h3.z, fmaf(w[13], h3.y, w[12] * h3.x)));        \
    float a4 = fmaf(w[19], h4.w, fmaf(w[18], h4.z, fmaf(w[17], h4.y, w[16] * h4.x)));        \
    float s_ = (a0 + a1) + ((a2 + a3) + a4);                                   \
    float hn = tanh_scaled(s_);                                                \
    __builtin_amdgcn_wave_barrier();                                           \
    hsh[g][j] = hn;                                                            \
    __builtin_amdgcn_wave_barrier();                                           \
  }

#pragma unroll
  for (int i = 0; i < PF; ++i) bufA[i] = xl[i * STRIDE];

  for (int c = 0; c < SEQ / PF; c += 2) {
#pragma unroll
    for (int i = 0; i < PF; ++i) bufB[i] = xl[((c + 1) * PF + i) * STRIDE];
#pragma unroll
    for (int i = 0; i < PF; ++i) STEPF(bufA[i]);
    if (c + 2 < SEQ / PF) {
#pragma unroll
      for (int i = 0; i < PF; ++i) bufA[i] = xl[((c + 2) * PF + i) * STRIDE];
    }
#pragma unroll
    for (int i = 0; i < PF; ++i) STEPF(bufB[i]);
  }

  // FC epilogue: out[b][c] = b_fc[c] + sum_k W_fc[c][k] * h_final[k]
  if (valid && j < NCLS) {
    float acc = b_fc[j];
#pragma unroll
    for (int k = 0; k < HID; ++k)
      acc = fmaf(W_fc[j * HID + k], hsh[g][k], acc);
    out[b * NCLS + j] = acc;
  }
#undef STEPF
}

// ---------------------------------------------------------------------------
extern "C" void kernel_launch(void* const* d_in, const int* in_sizes, int n_in,
                              void* d_out, int out_size, void* d_ws, size_t ws_size,
                              hipStream_t stream) {
  const float* x    = (const float*)d_in[0];
  const float* W_ih = (const float*)d_in[1];
  const float* W_hh = (const float*)d_in[2];
  const float* b_ih = (const float*)d_in[3];
  const float* b_hh = (const float*)d_in[4];
  const float* W_fc = (const float*)d_in[5];
  const float* b_fc = (const float*)d_in[6];
  float* out = (float*)d_out;

  float* xp = (float*)d_ws;  // SEQ*BATCH*HID floats = 41.9 MB

  // 32768 16-row tiles / 16 per wave = 2048 one-wave blocks (32KB LDS each
  // -> 5 blocks/CU resident; 3 tiles in flight per wave = 120KB/CU in flight)
  k_input_proj<<<2048, 64, 0, stream>>>(x, W_ih, b_ih, b_hh, xp);

  const int nblk = (BATCH + BPW - 1) / BPW;  // 342
  k_rnn_scan<<<nblk, 64, 0, stream>>>(xp, W_hh, W_fc, b_fc, out);
}

// Round 8
// 83.352 us; speedup vs baseline: 1.7067x; 1.7067x over previous
//
#include <hip/hip_runtime.h>
#include <math.h>

// Problem dims (fixed by the reference)
#define SEQ   512
#define BATCH 1024
#define NFEAT 128
#define HID   20
#define NCLS  10

#define NTILE   32            // 512 steps / 16-step tiles
#define XR_SLOT 8192          // one 16-step x tile (16 x 512 B)
#define XP_OFF  49152         // 3 producers x 2 x 8192 before this
#define XP_DW   80            // dwords per ring step-slot (320 B, 3x20 padded)
#define HSH_OFF (XP_OFF + 48 * XP_DW * 4)   // 64512
#define FLG_OFF (HSH_OFF + 320)             // 64832
#define SMEM_SZ (FLG_OFF + 16)              // 64848 <= 65536

typedef __attribute__((ext_vector_type(8))) short short8v;  // 8 bf16
typedef __attribute__((ext_vector_type(4))) float f32x4;    // MFMA 16x16 acc
typedef __attribute__((ext_vector_type(4))) unsigned int u32x4;

#define AS1 __attribute__((address_space(1)))
#define AS3 __attribute__((address_space(3)))

__device__ __forceinline__ float truncbf(float f) {
  return __uint_as_float(__float_as_uint(f) & 0xffff0000u);
}
__device__ __forceinline__ unsigned packhi2(float a, float b) {
  return (__float_as_uint(a) >> 16) | (__float_as_uint(b) & 0xffff0000u);
}
__device__ __forceinline__ short8v mk8(unsigned a, unsigned b, unsigned c, unsigned d) {
  u32x4 u; u[0] = a; u[1] = b; u[2] = c; u[3] = d;
  return __builtin_bit_cast(short8v, u);
}
// fp32 octet -> (hi bf16x8, lo bf16x8); x == hi + lo to ~2^-17 rel
__device__ __forceinline__ void cvt_hilo(float4 ca, float4 cb, short8v& hi, short8v& lo) {
  hi = mk8(packhi2(ca.x, ca.y), packhi2(ca.z, ca.w),
           packhi2(cb.x, cb.y), packhi2(cb.z, cb.w));
  const float l0 = ca.x - truncbf(ca.x);
  const float l1 = ca.y - truncbf(ca.y);
  const float l2 = ca.z - truncbf(ca.z);
  const float l3 = ca.w - truncbf(ca.w);
  const float l4 = cb.x - truncbf(cb.x);
  const float l5 = cb.y - truncbf(cb.y);
  const float l6 = cb.z - truncbf(cb.z);
  const float l7 = cb.w - truncbf(cb.w);
  lo = mk8(packhi2(l0, l1), packhi2(l2, l3), packhi2(l4, l5), packhi2(l6, l7));
}

__device__ __forceinline__ float tanh_scaled(float sp) {  // sp = 2*s
  sp = fminf(fmaxf(sp, -18.0f), 18.0f);
  const float e = __expf(sp);
  return (e - 1.0f) * __builtin_amdgcn_rcpf(e + 1.0f);
}

// ---------------------------------------------------------------------------
// Fused RNN: 342 blocks x 4 waves.
//   wave 0   = chain: 3 batches, 512-step recurrence + FC (LDS h-exchange,
//              xp read from the LDS ring, batch-16 into regs after a poll)
//   waves1-3 = producers: one batch each; per 16-step tile, MFMA
//              xp = 2*(x@W_ih^T + b) from x staged via global_load_lds
//              (2-deep ring, counted vmcnt -- all VM ops are loads), written
//              into a 48-step LDS ring guarded by acquire/release counters.
// No cross-block deps -> no cooperative launch needed. xp never hits HBM.
// ---------------------------------------------------------------------------
__global__ __launch_bounds__(256) void k_rnn_fused(
    const float* __restrict__ x, const float* __restrict__ W_ih,
    const float* __restrict__ W_hh, const float* __restrict__ b_ih,
    const float* __restrict__ b_hh, const float* __restrict__ W_fc,
    const float* __restrict__ b_fc, float* __restrict__ out)
{
  __shared__ __align__(16) char smem[SMEM_SZ];
  const int tid  = threadIdx.x;
  const int wv   = tid >> 6;
  const int lane = tid & 63;
  unsigned* prodp = (unsigned*)(smem + FLG_OFF);        // [3] producer progress
  unsigned* consp = (unsigned*)(smem + FLG_OFF + 12);   // consumer progress

  // init (owner-writes-first), then one barrier; no barriers after this
  if (wv == 0) {
    if (lane == 0) *consp = 0u;
    if (lane < 80) ((float*)(smem + HSH_OFF))[lane] = 0.0f;   // h0 = 0
  } else if (lane == 0) {
    const int bb = blockIdx.x * 3 + (wv - 1);
    prodp[wv - 1] = (bb < BATCH) ? 0u : (unsigned)SEQ;
  }
  __syncthreads();

#define LGKM0()    asm volatile("s_waitcnt lgkmcnt(0)" ::: "memory")
#define VM_WAIT(N) asm volatile("s_waitcnt vmcnt(" #N ")" ::: "memory")

  if (wv != 0) {
    // ================= producer =================
    const int g = wv - 1;
    const int b = blockIdx.x * 3 + g;
    if (b >= BATCH) return;                 // prog already = SEQ
    const int rr = lane & 15, kq = lane >> 4;

    // W_ih -> resident B fragments (hi/lo, 2 n-tiles x 4 k-chunks)
    short8v Bhi[2][4], Blo[2][4];
#pragma unroll
    for (int nt = 0; nt < 2; ++nt) {
      const int n = nt * 16 + rr;
      const bool v = (n < HID);
#pragma unroll
      for (int c = 0; c < 4; ++c) {
        float4 wa = {0.f,0.f,0.f,0.f}, wb = {0.f,0.f,0.f,0.f};
        if (v) {
          const float* wp = W_ih + n * NFEAT + c * 32 + kq * 8;
          wa = *reinterpret_cast<const float4*>(wp);
          wb = *reinterpret_cast<const float4*>(wp + 4);
        }
        cvt_hilo(wa, wb, Bhi[nt][c], Blo[nt][c]);
      }
    }
    const float badd0 = b_ih[rr] + b_hh[rr];
    const int   n1    = 16 + rr;
    const float badd1 = (n1 < HID) ? (b_ih[n1] + b_hh[n1]) : 0.0f;

    // per-lane DMA source offsets (pre-swizzled global, linear LDS dest)
    int srcb[8];
#pragma unroll
    for (int jj = 0; jj < 8; ++jj) {
      const int row = 2 * jj + (lane >> 5);          // step within tile
      srcb[jj] = row * 524288 + (((lane & 31) * 16) ^ ((row & 7) << 4));
    }
    // swizzled fragment-read bases within an 8KB tile
    const int rdp0 = (rr * 512 + kq * 32)      ^ ((rr & 7) << 4);
    const int rdp1 = (rr * 512 + kq * 32 + 16) ^ ((rr & 7) << 4);

    char* xr = smem + g * (2 * XR_SLOT);
    float* ring = (float*)(smem + XP_OFF);
    const char* xg = (const char*)x + (size_t)b * 512;  // x[t][b][0] = t*512KB + b*512

#define ISSUE(T) {                                                             \
    const char* gp_ = xg + (size_t)(T) * (16 * 524288);                        \
    char* db_ = xr + ((T) & 1) * XR_SLOT;                                      \
    _Pragma("unroll")                                                          \
    for (int jj = 0; jj < 8; ++jj)                                             \
      __builtin_amdgcn_global_load_lds(                                        \
          (const AS1 void*)(gp_ + srcb[jj]),                                   \
          (AS3 void*)(db_ + jj * 1024), 16, 0, 0); }

    ISSUE(0); ISSUE(1);

#pragma unroll 1
    for (int T = 0; T < NTILE; ++T) {
      if (T < NTILE - 1) { VM_WAIT(8); } else { VM_WAIT(0); }   // tile T resident
      const char* lb = xr + (T & 1) * XR_SLOT;
      float4 ca[4], cb[4];
#pragma unroll
      for (int c = 0; c < 4; ++c) {
        ca[c] = *reinterpret_cast<const float4*>(lb + rdp0 + c * 128);
        cb[c] = *reinterpret_cast<const float4*>(lb + rdp1 + c * 128);
      }
      LGKM0();                       // x data in regs -> slot reusable
      if (T + 2 < NTILE) ISSUE(T + 2);

      f32x4 acc0 = {0.f,0.f,0.f,0.f}, acc1 = {0.f,0.f,0.f,0.f};
#pragma unroll
      for (int c = 0; c < 4; ++c) {
        short8v Ahi, Alo;
        cvt_hilo(ca[c], cb[c], Ahi, Alo);
        acc0 = __builtin_amdgcn_mfma_f32_16x16x32_bf16(Ahi, Bhi[0][c], acc0, 0, 0, 0);
        acc0 = __builtin_amdgcn_mfma_f32_16x16x32_bf16(Ahi, Blo[0][c], acc0, 0, 0, 0);
        acc0 = __builtin_amdgcn_mfma_f32_16x16x32_bf16(Alo, Bhi[0][c], acc0, 0, 0, 0);
        acc1 = __builtin_amdgcn_mfma_f32_16x16x32_bf16(Ahi, Bhi[1][c], acc1, 0, 0, 0);
        acc1 = __builtin_amdgcn_mfma_f32_16x16x32_bf16(Ahi, Blo[1][c], acc1, 0, 0, 0);
        acc1 = __builtin_amdgcn_mfma_f32_16x16x32_bf16(Alo, Bhi[1][c], acc1, 0, 0, 0);
      }

      // ring-space check (ring = 3 tiles; tiles 0..2 need no check)
      if (T >= 3) {
        const unsigned need = (unsigned)((T - 2) * 16);
        while (__hip_atomic_load(consp, __ATOMIC_ACQUIRE,
                                 __HIP_MEMORY_SCOPE_WORKGROUP) < need)
          __builtin_amdgcn_s_sleep(2);
      }
      // write xp tile into ring: step = T*16 + kq*4 + reg; C col rr = hid
      const int sb = (T % 3) * 16;
#pragma unroll
      for (int reg = 0; reg < 4; ++reg) {
        float* p = ring + (sb + kq * 4 + reg) * XP_DW + g * 20;
        p[rr] = 2.0f * (acc0[reg] + badd0);
        if (n1 < HID) p[n1] = 2.0f * (acc1[reg] + badd1);
      }
      LGKM0();                       // ring writes visible before flag
      if (lane == 0)
        __hip_atomic_store(prodp + g, (unsigned)((T + 1) * 16),
                           __ATOMIC_RELEASE, __HIP_MEMORY_SCOPE_WORKGROUP);
    }
#undef ISSUE
    return;
  }

  // ================= chain (wave 0) =================
  {
    const int g = lane / HID;        // 0..3 (g==3 lanes compute garbage, masked)
    const int j = lane - g * HID;    // 0..19
    const int b = blockIdx.x * 3 + g;
    const bool valid = (g < 3) && (b < BATCH);

    // W_hh row j -> registers, pre-scaled by 2 (tanh chain shortening)
    float w[HID];
    {
      const float4* wr = reinterpret_cast<const float4*>(W_hh + j * HID);
#pragma unroll
      for (int qq = 0; qq < HID / 4; ++qq) {
        const float4 v = wr[qq];
        w[qq*4+0] = 2.0f*v.x; w[qq*4+1] = 2.0f*v.y;
        w[qq*4+2] = 2.0f*v.z; w[qq*4+3] = 2.0f*v.w;
      }
    }
    float* hshp = (float*)(smem + HSH_OFF);
    const float4* hp = reinterpret_cast<const float4*>(hshp + g * HID);
    float* hme = hshp + g * HID + j;
    const float* ringc = (const float*)(smem + XP_OFF);

#define STEPF(XV)                                                              \
  {                                                                            \
    float4 h0 = hp[0], h1 = hp[1], h2 = hp[2], h3 = hp[3], h4 = hp[4];         \
    float a0 = fmaf(w[3], h0.w, fmaf(w[2], h0.z, fmaf(w[1], h0.y, fmaf(w[0], h0.x, (XV))))); \
    float a1 = fmaf(w[7], h1.w, fmaf(w[6], h1.z, fmaf(w[5], h1.y, w[4] * h1.x)));            \
    float a2 = fmaf(w[11], h2.w, fmaf(w[10], h2.z, fmaf(w[9], h2.y, w[8] * h2.x)));          \
    float a3 = fmaf(w[15], h3.w, fmaf(w[14], h3.z, fmaf(w[13], h3.y, w[12] * h3.x)));        \
    float a4 = fmaf(w[19], h4.w, fmaf(w[18], h4.z, fmaf(w[17], h4.y, w[16] * h4.x)));        \
    float s_ = (a0 + a1) + ((a2 + a3) + a4);                                   \
    float hn = tanh_scaled(s_);                                                \
    __builtin_amdgcn_wave_barrier();                                           \
    *hme = hn;                                                                 \
    __builtin_amdgcn_wave_barrier();                                           \
  }

#pragma unroll 1
    for (int tile = 0; tile < NTILE; ++tile) {
      const unsigned need = (unsigned)((tile + 1) * 16);
#pragma unroll
      for (int gg = 0; gg < 3; ++gg)
        while (__hip_atomic_load(prodp + gg, __ATOMIC_ACQUIRE,
                                 __HIP_MEMORY_SCOPE_WORKGROUP) < need)
          __builtin_amdgcn_s_sleep(2);

      // batch-read this tile's 16 xp values into registers
      const float* xb0 = ringc + (tile % 3) * 16 * XP_DW + g * 20 + j;
      float xv[16];
#pragma unroll
      for (int i = 0; i < 16; ++i) xv[i] = xb0[i * XP_DW];
      LGKM0();                       // reads retired -> slots reusable
      if (lane == 0)
        __hip_atomic_store(consp, (unsigned)((tile + 1) * 16),
                           __ATOMIC_RELEASE, __HIP_MEMORY_SCOPE_WORKGROUP);

#pragma unroll
      for (int i = 0; i < 16; ++i) STEPF(xv[i]);
    }

    // FC epilogue: out[b][c] = b_fc[c] + sum_k W_fc[c][k] * h_final[k]
    if (valid && j < NCLS) {
      float acc = b_fc[j];
#pragma unroll
      for (int k = 0; k < HID; ++k)
        acc = fmaf(W_fc[j * HID + k], hshp[g * HID + k], acc);
      out[b * NCLS + j] = acc;
    }
#undef STEPF
  }
#undef LGKM0
#undef VM_WAIT
}

// ---------------------------------------------------------------------------
extern "C" void kernel_launch(void* const* d_in, const int* in_sizes, int n_in,
                              void* d_out, int out_size, void* d_ws, size_t ws_size,
                              hipStream_t stream) {
  const float* x    = (const float*)d_in[0];
  const float* W_ih = (const float*)d_in[1];
  const float* W_hh = (const float*)d_in[2];
  const float* b_ih = (const float*)d_in[3];
  const float* b_hh = (const float*)d_in[4];
  const float* W_fc = (const float*)d_in[5];
  const float* b_fc = (const float*)d_in[6];
  float* out = (float*)d_out;

  const int nblk = (BATCH + 2) / 3;  // 342 independent blocks
  k_rnn_fused<<<nblk, 256, 0, stream>>>(x, W_ih, W_hh, b_ih, b_hh, W_fc, b_fc, out);
}

// Round 9
// 74.283 us; speedup vs baseline: 1.9150x; 1.1221x over previous
//
#include <hip/hip_runtime.h>
#include <math.h>

// Problem dims (fixed by the reference)
#define SEQ   512
#define BATCH 1024
#define NFEAT 128
#define HID   20
#define NCLS  10

#define NTILE  32      // 512 steps / 16-step tiles
#define XP_DW  84      // dwords per ring step-slot (4*20 + 4 pad; 2-way banks max)
#define RSTEPS 48      // ring = 3 tiles x 16 steps

typedef __attribute__((ext_vector_type(8))) short short8v;  // 8 bf16
typedef __attribute__((ext_vector_type(4))) float f32x4;    // MFMA 16x16 acc
typedef __attribute__((ext_vector_type(4))) unsigned int u32x4;

__device__ __forceinline__ float truncbf(float f) {
  return __uint_as_float(__float_as_uint(f) & 0xffff0000u);
}
__device__ __forceinline__ unsigned packhi2(float a, float b) {
  return (__float_as_uint(a) >> 16) | (__float_as_uint(b) & 0xffff0000u);
}
__device__ __forceinline__ short8v mk8(unsigned a, unsigned b, unsigned c, unsigned d) {
  u32x4 u; u[0] = a; u[1] = b; u[2] = c; u[3] = d;
  return __builtin_bit_cast(short8v, u);
}
// fp32 octet -> (hi bf16x8, lo bf16x8); x == hi + lo to ~2^-17 rel
__device__ __forceinline__ void cvt_hilo(float4 ca, float4 cb, short8v& hi, short8v& lo) {
  hi = mk8(packhi2(ca.x, ca.y), packhi2(ca.z, ca.w),
           packhi2(cb.x, cb.y), packhi2(cb.z, cb.w));
  const float l0 = ca.x - truncbf(ca.x);
  const float l1 = ca.y - truncbf(ca.y);
  const float l2 = ca.z - truncbf(ca.z);
  const float l3 = ca.w - truncbf(ca.w);
  const float l4 = cb.x - truncbf(cb.x);
  const float l5 = cb.y - truncbf(cb.y);
  const float l6 = cb.z - truncbf(cb.z);
  const float l7 = cb.w - truncbf(cb.w);
  lo = mk8(packhi2(l0, l1), packhi2(l2, l3), packhi2(l4, l5), packhi2(l6, l7));
}

__device__ __forceinline__ float tanh_scaled(float sp) {  // sp = 2*s
  sp = fminf(fmaxf(sp, -18.0f), 18.0f);
  const float e = __expf(sp);
  return (e - 1.0f) * __builtin_amdgcn_rcpf(e + 1.0f);
}

// ---------------------------------------------------------------------------
// Fused RNN, balanced: 256 blocks x 4 batches, exactly 1 block/CU.
//   waves 0-1 = chains: 2 batches each (40 lanes = 2 x 20), 512-step
//               recurrence + FC; xp read from LDS ring.
//   waves 2-5 = producers: one batch each; per 16-step tile MFMA
//               xp = 2*(x@W_ih^T + b) with x loaded REGISTER-DIRECT,
//               3 tiles (24 KB) in flight per producer (96 KB/CU),
//               compiler-managed vmcnt (no DMA, no counting hazards).
// LDS: only the 48-step xp ring (16.1 KB) + h + flags. No 64KB-cap issues.
// ---------------------------------------------------------------------------
__global__ __launch_bounds__(384) void k_rnn_fused(
    const float* __restrict__ x, const float* __restrict__ W_ih,
    const float* __restrict__ W_hh, const float* __restrict__ b_ih,
    const float* __restrict__ b_hh, const float* __restrict__ W_fc,
    const float* __restrict__ b_fc, float* __restrict__ out)
{
  __shared__ __align__(16) float ring[RSTEPS * XP_DW];  // 16128 B
  __shared__ __align__(16) float hsh[4 * HID];          // 320 B
  __shared__ unsigned prodp[4];
  __shared__ unsigned consp[2];

  const int tid  = threadIdx.x;
  const int wv   = tid >> 6;
  const int lane = tid & 63;

  // init (owner-writes), one barrier, then flag-based sync only
  if (wv == 0) {
    hsh[lane < 80 ? lane : 0] = 0.0f;
    if (lane < 16) hsh[64 + lane] = 0.0f;
    if (lane < 2) consp[lane] = 0u;
  } else if (wv >= 2 && lane == 0) {
    prodp[wv - 2] = 0u;
  }
  __syncthreads();

#define LGKM0() asm volatile("s_waitcnt lgkmcnt(0)" ::: "memory")
#define POLL_GE(PTR, VAL)                                                      \
  while (__hip_atomic_load((PTR), __ATOMIC_ACQUIRE,                            \
                           __HIP_MEMORY_SCOPE_WORKGROUP) < (unsigned)(VAL))    \
    __builtin_amdgcn_s_sleep(1)

  if (wv >= 2) {
    // ========================= producer =========================
    const int g  = wv - 2;
    const int b  = blockIdx.x * 4 + g;      // 256*4 = 1024 exact, no guards
    const int rr = lane & 15, kq = lane >> 4;

    // W_ih -> resident B fragments (hi/lo, 2 n-tiles x 4 k-chunks)
    short8v Bhi[2][4], Blo[2][4];
#pragma unroll
    for (int nt = 0; nt < 2; ++nt) {
      const int n = nt * 16 + rr;
      const bool v = (n < HID);
#pragma unroll
      for (int c = 0; c < 4; ++c) {
        float4 wa = {0.f,0.f,0.f,0.f}, wb = {0.f,0.f,0.f,0.f};
        if (v) {
          const float* wp = W_ih + n * NFEAT + c * 32 + kq * 8;
          wa = *reinterpret_cast<const float4*>(wp);
          wb = *reinterpret_cast<const float4*>(wp + 4);
        }
        cvt_hilo(wa, wb, Bhi[nt][c], Blo[nt][c]);
      }
    }
    const float badd0 = b_ih[rr] + b_hh[rr];
    const int   n1    = 16 + rr;
    const float badd1 = (n1 < HID) ? (b_ih[n1] + b_hh[n1]) : 0.0f;

    // lane's x base: x[t][b][kq*8], step stride = 1024*128 floats
    const float* __restrict__ xlane = x + (size_t)b * NFEAT + kq * 8;
    unsigned* myflag = prodp + g;
    unsigned* cflag  = consp + (g >> 1);

#define LD4(P) (*reinterpret_cast<const float4*>(P))
#define LOADT(BUF, T) {                                                        \
    const float* rp_ = xlane + (size_t)((T) * 16 + rr) * (BATCH * NFEAT);      \
    BUF[0] = LD4(rp_ +  0); BUF[1] = LD4(rp_ +  4);                            \
    BUF[2] = LD4(rp_ + 32); BUF[3] = LD4(rp_ + 36);                            \
    BUF[4] = LD4(rp_ + 64); BUF[5] = LD4(rp_ + 68);                            \
    BUF[6] = LD4(rp_ + 96); BUF[7] = LD4(rp_ + 100); }

#define COMPSTORE(BUF, T) {                                                    \
    if ((T) >= 3) { POLL_GE(cflag, ((T) - 2) * 16); }                          \
    f32x4 acc0 = {0.f,0.f,0.f,0.f}, acc1 = {0.f,0.f,0.f,0.f};                  \
    _Pragma("unroll")                                                          \
    for (int c = 0; c < 4; ++c) {                                              \
      short8v Ahi, Alo;                                                        \
      cvt_hilo(BUF[2*c], BUF[2*c+1], Ahi, Alo);                                \
      acc0 = __builtin_amdgcn_mfma_f32_16x16x32_bf16(Ahi, Bhi[0][c], acc0, 0, 0, 0); \
      acc0 = __builtin_amdgcn_mfma_f32_16x16x32_bf16(Ahi, Blo[0][c], acc0, 0, 0, 0); \
      acc0 = __builtin_amdgcn_mfma_f32_16x16x32_bf16(Alo, Bhi[0][c], acc0, 0, 0, 0); \
      acc1 = __builtin_amdgcn_mfma_f32_16x16x32_bf16(Ahi, Bhi[1][c], acc1, 0, 0, 0); \
      acc1 = __builtin_amdgcn_mfma_f32_16x16x32_bf16(Ahi, Blo[1][c], acc1, 0, 0, 0); \
      acc1 = __builtin_amdgcn_mfma_f32_16x16x32_bf16(Alo, Bhi[1][c], acc1, 0, 0, 0); \
    }                                                                          \
    const int sb = ((T) % 3) * 16;                                             \
    _Pragma("unroll")                                                          \
    for (int reg = 0; reg < 4; ++reg) {                                        \
      float* p = ring + (sb + kq * 4 + reg) * XP_DW + g * HID;                 \
      p[rr] = 2.0f * (acc0[reg] + badd0);                                      \
      if (n1 < HID) p[n1] = 2.0f * (acc1[reg] + badd1);                        \
    }                                                                          \
    LGKM0();                                                                   \
    if (lane == 0)                                                             \
      __hip_atomic_store(myflag, (unsigned)(((T) + 1) * 16),                   \
                         __ATOMIC_RELEASE, __HIP_MEMORY_SCOPE_WORKGROUP); }

    float4 sA[8], sB[8], sC[8];       // 3 tiles (24 KB) in flight, static idx
    LOADT(sA, 0); LOADT(sB, 1); LOADT(sC, 2);

#pragma unroll 1
    for (int t = 0; t < 30; t += 3) {
      COMPSTORE(sA, t);     if (t + 3 < NTILE) LOADT(sA, t + 3);
      COMPSTORE(sB, t + 1); if (t + 4 < NTILE) LOADT(sB, t + 4);
      COMPSTORE(sC, t + 2); if (t + 5 < NTILE) LOADT(sC, t + 5);
    }
    COMPSTORE(sA, 30);
    COMPSTORE(sB, 31);
#undef LOADT
#undef COMPSTORE
#undef LD4
    return;
  }

  // ========================= chains (waves 0,1) =========================
  {
    const int cw  = wv;                       // chain wave id
    const int l2  = lane < 40 ? lane : 39;    // lanes 40..63 mirror lane 39
    const int grp = l2 / HID;                 // 0..1
    const int j   = l2 - grp * HID;           // 0..19
    const int g   = cw * 2 + grp;             // global group 0..3
    const int b   = blockIdx.x * 4 + g;

    // W_hh row j -> registers, pre-scaled by 2 (tanh chain shortening)
    float w[HID];
    {
      const float4* wr = reinterpret_cast<const float4*>(W_hh + j * HID);
#pragma unroll
      for (int qq = 0; qq < HID / 4; ++qq) {
        const float4 v = wr[qq];
        w[qq*4+0] = 2.0f*v.x; w[qq*4+1] = 2.0f*v.y;
        w[qq*4+2] = 2.0f*v.z; w[qq*4+3] = 2.0f*v.w;
      }
    }
    const float4* hp  = reinterpret_cast<const float4*>(hsh + g * HID);
    float*        hme = hsh + g * HID + j;
    unsigned* p0 = prodp + cw * 2;
    unsigned* p1 = prodp + cw * 2 + 1;
    unsigned* myc = consp + cw;

#define STEPF(XV)                                                              \
  {                                                                            \
    float4 h0 = hp[0], h1 = hp[1], h2 = hp[2], h3 = hp[3], h4 = hp[4];         \
    float a0 = fmaf(w[3], h0.w, fmaf(w[2], h0.z, fmaf(w[1], h0.y, fmaf(w[0], h0.x, (XV))))); \
    float a1 = fmaf(w[7], h1.w, fmaf(w[6], h1.z, fmaf(w[5], h1.y, w[4] * h1.x)));            \
    float a2 = fmaf(w[11], h2.w, fmaf(w[10], h2.z, fmaf(w[9], h2.y, w[8] * h2.x)));          \
    float a3 = fmaf(w[15], h3.w, fmaf(w[14], h3.z, fmaf(w[13], h3.y, w[12] * h3.x)));        \
    float a4 = fmaf(w[19], h4.w, fmaf(w[18], h4.z, fmaf(w[17], h4.y, w[16] * h4.x)));        \
    float s_ = (a0 + a1) + ((a2 + a3) + a4);                                   \
    float hn = tanh_scaled(s_);                                                \
    __builtin_amdgcn_wave_barrier();                                           \
    *hme = hn;                                                                 \
    __builtin_amdgcn_wave_barrier();                                           \
  }

#pragma unroll 1
    for (int tile = 0; tile < NTILE; ++tile) {
      const unsigned need = (unsigned)((tile + 1) * 16);
      POLL_GE(p0, need);
      POLL_GE(p1, need);

      // batch-read this tile's 16 xp values into registers
      const float* xb0 = ring + (tile % 3) * 16 * XP_DW + g * HID + j;
      float xv[16];
#pragma unroll
      for (int i = 0; i < 16; ++i) xv[i] = xb0[i * XP_DW];
      LGKM0();                      // reads retired -> slots reusable
      if (lane == 0)
        __hip_atomic_store(myc, (unsigned)((tile + 1) * 16),
                           __ATOMIC_RELEASE, __HIP_MEMORY_SCOPE_WORKGROUP);

#pragma unroll
      for (int i = 0; i < 16; ++i) STEPF(xv[i]);
    }

    // FC epilogue: out[b][c] = b_fc[c] + sum_k W_fc[c][k] * h_final[k]
    if (lane < 40 && j < NCLS) {
      float acc = b_fc[j];
#pragma unroll
      for (int k = 0; k < HID; ++k)
        acc = fmaf(W_fc[j * HID + k], hsh[g * HID + k], acc);
      out[b * NCLS + j] = acc;
    }
#undef STEPF
  }
#undef LGKM0
#undef POLL_GE
}

// ---------------------------------------------------------------------------
extern "C" void kernel_launch(void* const* d_in, const int* in_sizes, int n_in,
                              void* d_out, int out_size, void* d_ws, size_t ws_size,
                              hipStream_t stream) {
  const float* x    = (const float*)d_in[0];
  const float* W_ih = (const float*)d_in[1];
  const float* W_hh = (const float*)d_in[2];
  const float* b_ih = (const float*)d_in[3];
  const float* b_hh = (const float*)d_in[4];
  const float* W_fc = (const float*)d_in[5];
  const float* b_fc = (const float*)d_in[6];
  float* out = (float*)d_out;

  // 256 blocks x 4 batches = 1024; exactly one 6-wave block per CU
  k_rnn_fused<<<BATCH / 4, 384, 0, stream>>>(x, W_ih, W_hh, b_ih, b_hh,
                                             W_fc, b_fc, out);
}